// Round 2
// baseline (414.055 us; speedup 1.0000x reference)
//
#include <hip/hip_runtime.h>
#include <hip/hip_bf16.h>

#define NNODES 2048
#define NHEAD 8
#define DKDIM 64

// ---------------- CSR build kernels ----------------

__global__ void hist_kernel(const int4* __restrict__ dst4, int* __restrict__ counts, int E4) {
    int i = blockIdx.x * blockDim.x + threadIdx.x;
    if (i < E4) {
        int4 d = dst4[i];
        atomicAdd(&counts[d.x], 1);
        atomicAdd(&counts[d.y], 1);
        atomicAdd(&counts[d.z], 1);
        atomicAdd(&counts[d.w], 1);
    }
}

// single block, 256 threads, N = 2048 (8 elements per thread)
__global__ void scan_kernel(const int* __restrict__ counts, int* __restrict__ offsets,
                            int* __restrict__ cursor) {
    int t = threadIdx.x;
    int local[8];
    int sum = 0;
#pragma unroll
    for (int i = 0; i < 8; ++i) { local[i] = counts[t * 8 + i]; sum += local[i]; }

    int lane = t & 63, wid = t >> 6;
    int x = sum;
#pragma unroll
    for (int d = 1; d < 64; d <<= 1) {
        int y = __shfl_up(x, d);
        if (lane >= d) x += y;
    }
    __shared__ int wsum[4];
    if (lane == 63) wsum[wid] = x;
    __syncthreads();
    int wbase = 0;
    for (int w = 0; w < wid; ++w) wbase += wsum[w];
    int excl = wbase + x - sum;
    int run = excl;
#pragma unroll
    for (int i = 0; i < 8; ++i) {
        offsets[t * 8 + i] = run;
        cursor[t * 8 + i] = run;
        run += local[i];
    }
    if (t == 255) offsets[NNODES] = run;
}

__global__ void scatter_kernel(const int4* __restrict__ src4, const int4* __restrict__ dst4,
                               int* __restrict__ cursor, int* __restrict__ src_sorted, int E4) {
    int i = blockIdx.x * blockDim.x + threadIdx.x;
    if (i < E4) {
        int4 s = src4[i];
        int4 d = dst4[i];
        src_sorted[atomicAdd(&cursor[d.x], 1)] = s.x;
        src_sorted[atomicAdd(&cursor[d.y], 1)] = s.y;
        src_sorted[atomicAdd(&cursor[d.z], 1)] = s.z;
        src_sorted[atomicAdd(&cursor[d.w], 1)] = s.w;
    }
}

// ---------------- main attention kernel ----------------
// One block per destination node, 256 threads.
// Chunked over edges (32 per chunk):
//   score phase: thread = (edge e, head h); full 64-dim dot, no cross-lane.
//   agg   phase: thread = (head ah, dim-pair); FMA v[src] * score from LDS.
__global__ void __launch_bounds__(256, 8) attn_kernel(
    const float* __restrict__ q, const float* __restrict__ k, const float* __restrict__ v,
    const int* __restrict__ offsets, const int* __restrict__ src_sorted,
    float* __restrict__ out) {
    __shared__ float q_lds[NHEAD * 68];   // 68-float rows: 16B-aligned, bank-staggered
    __shared__ float sc[32 * NHEAD];
    __shared__ int s_src[32];

    int node = blockIdx.x;
    int t = threadIdx.x;

    // stage q[node] (2 KB) into LDS, padded rows
    if (t < 128) {
        int h = t >> 4;
        int i4 = t & 15;
        float4 qq = ((const float4*)q)[node * (NHEAD * DKDIM / 4) + t];
        *((float4*)&q_lds[h * 68 + i4 * 4]) = qq;
    }

    int beg = offsets[node];
    int end = offsets[node + 1];
    int deg = end - beg;

    // aggregation identity
    int wave = t >> 6, lane = t & 63;
    int ah = (wave << 1) | (lane >> 5);   // head 0..7
    int dpair = lane & 31;                // float2 index in DK

    // score identity
    int se = t >> 3;                      // edge-in-chunk 0..31
    int sh = t & 7;                       // head 0..7

    float acc0 = 0.f, acc1 = 0.f, zacc = 0.f;

    __syncthreads();

    for (int base = 0; base < deg; base += 32) {
        int cnt = min(32, deg - base);

        // ---- score phase ----
        if (se < cnt) {
            int src = src_sorted[beg + base + se];
            if (sh == 0) s_src[se] = src;
            const float4* krow = (const float4*)&k[((size_t)src * NHEAD + sh) * DKDIM];
            const float4* qrow = (const float4*)&q_lds[sh * 68];
            float d0 = 0.f, d1 = 0.f, d2 = 0.f, d3 = 0.f;
#pragma unroll
            for (int i = 0; i < 16; ++i) {
                float4 kk = krow[i];
                float4 qq = qrow[i];
                d0 = fmaf(kk.x, qq.x, d0);
                d1 = fmaf(kk.y, qq.y, d1);
                d2 = fmaf(kk.z, qq.z, d2);
                d3 = fmaf(kk.w, qq.w, d3);
            }
            float s = ((d0 + d1) + (d2 + d3)) * 0.125f;
            s = fminf(fmaxf(s, -10.f), 10.f);
            sc[se * NHEAD + sh] = __expf(s);
        }
        __syncthreads();

        // ---- aggregation phase ----
        for (int e = 0; e < cnt; ++e) {
            int src = s_src[e];
            float s = sc[e * NHEAD + ah];
            float2 vv = ((const float2*)v)[((size_t)src * NHEAD + ah) * (DKDIM / 2) + dpair];
            acc0 = fmaf(s, vv.x, acc0);
            acc1 = fmaf(s, vv.y, acc1);
            zacc += s;
        }
        __syncthreads();
    }

    float inv = 1.0f / zacc;
    float2 o;
    o.x = acc0 * inv;
    o.y = acc1 * inv;
    ((float2*)out)[((size_t)node * NHEAD + ah) * (DKDIM / 2) + dpair] = o;
}

// ---------------- launch ----------------

extern "C" void kernel_launch(void* const* d_in, const int* in_sizes, int n_in,
                              void* d_out, int out_size, void* d_ws, size_t ws_size,
                              hipStream_t stream) {
    const float* q = (const float*)d_in[0];
    const float* k = (const float*)d_in[1];
    const float* v = (const float*)d_in[2];
    const int* esrc = (const int*)d_in[3];
    const int* edst = (const int*)d_in[4];
    float* out = (float*)d_out;

    const int E = in_sizes[3];
    const int N = NNODES;
    const int E4 = E / 4;

    int* counts = (int*)d_ws;            // N
    int* offsets = counts + N;           // N+1
    int* cursor = offsets + N + 1;       // N
    int* src_sorted = cursor + N;        // E

    hipMemsetAsync(counts, 0, N * sizeof(int), stream);
    hist_kernel<<<(E4 + 255) / 256, 256, 0, stream>>>((const int4*)edst, counts, E4);
    scan_kernel<<<1, 256, 0, stream>>>(counts, offsets, cursor);
    scatter_kernel<<<(E4 + 255) / 256, 256, 0, stream>>>((const int4*)esrc, (const int4*)edst,
                                                         cursor, src_sorted, E4);
    attn_kernel<<<N, 256, 0, stream>>>(q, k, v, offsets, src_sorted, out);
}

// Round 3
// 301.328 us; speedup vs baseline: 1.3741x; 1.3741x over previous
//
#include <hip/hip_runtime.h>
#include <hip/hip_bf16.h>

#define NNODES 2048
#define NHEAD 8
#define DKDIM 64

// ---------------- CSR build kernels ----------------

__global__ void hist_kernel(const int4* __restrict__ dst4, int* __restrict__ counts, int E4) {
    int i = blockIdx.x * blockDim.x + threadIdx.x;
    if (i < E4) {
        int4 d = dst4[i];
        atomicAdd(&counts[d.x], 1);
        atomicAdd(&counts[d.y], 1);
        atomicAdd(&counts[d.z], 1);
        atomicAdd(&counts[d.w], 1);
    }
}

// single block, 256 threads, N = 2048 (8 elements per thread)
__global__ void scan_kernel(const int* __restrict__ counts, int* __restrict__ offsets,
                            int* __restrict__ cursor) {
    int t = threadIdx.x;
    int local[8];
    int sum = 0;
#pragma unroll
    for (int i = 0; i < 8; ++i) { local[i] = counts[t * 8 + i]; sum += local[i]; }

    int lane = t & 63, wid = t >> 6;
    int x = sum;
#pragma unroll
    for (int d = 1; d < 64; d <<= 1) {
        int y = __shfl_up(x, d);
        if (lane >= d) x += y;
    }
    __shared__ int wsum[4];
    if (lane == 63) wsum[wid] = x;
    __syncthreads();
    int wbase = 0;
    for (int w = 0; w < wid; ++w) wbase += wsum[w];
    int excl = wbase + x - sum;
    int run = excl;
#pragma unroll
    for (int i = 0; i < 8; ++i) {
        offsets[t * 8 + i] = run;
        cursor[t * 8 + i] = run;
        run += local[i];
    }
    if (t == 255) offsets[NNODES] = run;
}

__global__ void scatter_kernel(const int4* __restrict__ src4, const int4* __restrict__ dst4,
                               int* __restrict__ cursor, int* __restrict__ src_sorted, int E4) {
    int i = blockIdx.x * blockDim.x + threadIdx.x;
    if (i < E4) {
        int4 s = src4[i];
        int4 d = dst4[i];
        src_sorted[atomicAdd(&cursor[d.x], 1)] = s.x;
        src_sorted[atomicAdd(&cursor[d.y], 1)] = s.y;
        src_sorted[atomicAdd(&cursor[d.z], 1)] = s.z;
        src_sorted[atomicAdd(&cursor[d.w], 1)] = s.w;
    }
}

// ---------------- main attention kernel ----------------
// One block per destination node, 256 threads = 4 waves.
// Lane layout: head = lane>>3 (8 heads/wave), sub = lane&7 (8 dims each, 2x float4).
// Each wave processes edges e = wave, wave+4, ... : per edge one coalesced
// 2KB k-row + 2KB v-row gather, 8-FMA dot, 3-level shuffle reduce, exp, FMA-acc.
// Final cross-wave combine via LDS.
__global__ void __launch_bounds__(256, 6) attn_kernel(
    const float* __restrict__ q, const float* __restrict__ k, const float* __restrict__ v,
    const int* __restrict__ offsets, const int* __restrict__ src_sorted,
    float* __restrict__ out) {
    int node = blockIdx.x;
    int t = threadIdx.x;
    int w = t >> 6;
    int lane = t & 63;
    int head = lane >> 3;
    int sub = lane & 7;

    size_t qbase = ((size_t)node * NHEAD + head) * DKDIM + sub * 8;
    float4 q0 = *(const float4*)&q[qbase];
    float4 q1 = *(const float4*)&q[qbase + 4];

    int beg = offsets[node];
    int deg = offsets[node + 1] - beg;

    float4 a0 = {0.f, 0.f, 0.f, 0.f};
    float4 a1 = {0.f, 0.f, 0.f, 0.f};
    float z = 0.f;

#pragma unroll 2
    for (int e = w; e < deg; e += 4) {
        int src = src_sorted[beg + e];
        size_t base = ((size_t)src * NHEAD + head) * DKDIM + sub * 8;
        float4 k0 = *(const float4*)&k[base];
        float4 k1 = *(const float4*)&k[base + 4];
        float4 v0 = *(const float4*)&v[base];
        float4 v1 = *(const float4*)&v[base + 4];

        float pa = k0.x * q0.x;
        float pb = k0.y * q0.y;
        pa = fmaf(k0.z, q0.z, pa);
        pb = fmaf(k0.w, q0.w, pb);
        pa = fmaf(k1.x, q1.x, pa);
        pb = fmaf(k1.y, q1.y, pb);
        pa = fmaf(k1.z, q1.z, pa);
        pb = fmaf(k1.w, q1.w, pb);
        float p = pa + pb;
        p += __shfl_xor(p, 1);
        p += __shfl_xor(p, 2);
        p += __shfl_xor(p, 4);

        float sc = fminf(fmaxf(p * 0.125f, -10.f), 10.f);
        float s = __expf(sc);

        a0.x = fmaf(s, v0.x, a0.x);
        a0.y = fmaf(s, v0.y, a0.y);
        a0.z = fmaf(s, v0.z, a0.z);
        a0.w = fmaf(s, v0.w, a0.w);
        a1.x = fmaf(s, v1.x, a1.x);
        a1.y = fmaf(s, v1.y, a1.y);
        a1.z = fmaf(s, v1.z, a1.z);
        a1.w = fmaf(s, v1.w, a1.w);
        z += s;
    }

    // cross-wave reduction
    __shared__ float racc[4][64][9];   // padded stride 9 to dodge bank conflicts
    __shared__ float rz[4][8];
    float* row = &racc[w][lane][0];
    row[0] = a0.x; row[1] = a0.y; row[2] = a0.z; row[3] = a0.w;
    row[4] = a1.x; row[5] = a1.y; row[6] = a1.z; row[7] = a1.w;
    if (sub == 0) rz[w][head] = z;
    __syncthreads();

    // 512 outputs; thread t handles outputs t and t+256
#pragma unroll
    for (int i = t; i < NHEAD * DKDIM; i += 256) {
        int l = i >> 3;        // lane that produced it
        int d8 = i & 7;
        int h = i >> 6;
        float sum = racc[0][l][d8] + racc[1][l][d8] + racc[2][l][d8] + racc[3][l][d8];
        float zz = rz[0][h] + rz[1][h] + rz[2][h] + rz[3][h];
        out[(size_t)node * NHEAD * DKDIM + i] = sum / zz;
    }
}

// ---------------- launch ----------------

extern "C" void kernel_launch(void* const* d_in, const int* in_sizes, int n_in,
                              void* d_out, int out_size, void* d_ws, size_t ws_size,
                              hipStream_t stream) {
    const float* q = (const float*)d_in[0];
    const float* k = (const float*)d_in[1];
    const float* v = (const float*)d_in[2];
    const int* esrc = (const int*)d_in[3];
    const int* edst = (const int*)d_in[4];
    float* out = (float*)d_out;

    const int E = in_sizes[3];
    const int N = NNODES;
    const int E4 = E / 4;

    int* counts = (int*)d_ws;            // N
    int* offsets = counts + N;           // N+1
    int* cursor = offsets + N + 1;       // N
    int* src_sorted = cursor + N;        // E

    hipMemsetAsync(counts, 0, N * sizeof(int), stream);
    hist_kernel<<<(E4 + 255) / 256, 256, 0, stream>>>((const int4*)edst, counts, E4);
    scan_kernel<<<1, 256, 0, stream>>>(counts, offsets, cursor);
    scatter_kernel<<<(E4 + 255) / 256, 256, 0, stream>>>((const int4*)esrc, (const int4*)edst,
                                                         cursor, src_sorted, E4);
    attn_kernel<<<N, 256, 0, stream>>>(q, k, v, offsets, src_sorted, out);
}

// Round 4
// 287.993 us; speedup vs baseline: 1.4377x; 1.0463x over previous
//
#include <hip/hip_runtime.h>

#define NNODES 2048
#define NHEAD 8
#define DKDIM 64
#define NB 256      // hist/scatter blocks
#define EPB 2048    // edges per block: NB*EPB = E = 524288

typedef unsigned int uint;
typedef unsigned short ushort;

__device__ __forceinline__ ushort f2bf(float f) {
    uint u = __float_as_uint(f);
    u = (u + 0x7FFFu + ((u >> 16) & 1u)) >> 16;   // RNE
    return (ushort)u;
}
#define BFLO(w) __uint_as_float((w) << 16)
#define BFHI(w) __uint_as_float((w) & 0xFFFF0000u)

// ---- k,v -> bf16 (k pre-scaled by 1/sqrt(64)) ----
__global__ void conv_kernel(const float4* __restrict__ kk, const float4* __restrict__ vv,
                            ushort4* __restrict__ kc, ushort4* __restrict__ vc) {
    int i = blockIdx.x * blockDim.x + threadIdx.x;   // 0 .. 524287
    if (i < 262144) {
        float4 x = kk[i];
        ushort4 o;
        o.x = f2bf(x.x * 0.125f); o.y = f2bf(x.y * 0.125f);
        o.z = f2bf(x.z * 0.125f); o.w = f2bf(x.w * 0.125f);
        kc[i] = o;
    } else {
        int j = i - 262144;
        float4 x = vv[j];
        ushort4 o;
        o.x = f2bf(x.x); o.y = f2bf(x.y); o.z = f2bf(x.z); o.w = f2bf(x.w);
        vc[j] = o;
    }
}

// ---- counting-sort CSR: pass A (LDS-private histogram) ----
__global__ void hist_kernel(const int4* __restrict__ dst4, int* __restrict__ bcounts) {
    __shared__ int lh[NNODES];
    int b = blockIdx.x, t = threadIdx.x;
    for (int j = t; j < NNODES; j += 256) lh[j] = 0;
    __syncthreads();
    const int4* p = dst4 + b * (EPB / 4);
    int4 d0 = p[t];
    int4 d1 = p[t + 256];
    atomicAdd(&lh[d0.x], 1); atomicAdd(&lh[d0.y], 1);
    atomicAdd(&lh[d0.z], 1); atomicAdd(&lh[d0.w], 1);
    atomicAdd(&lh[d1.x], 1); atomicAdd(&lh[d1.y], 1);
    atomicAdd(&lh[d1.z], 1); atomicAdd(&lh[d1.w], 1);
    __syncthreads();
    for (int j = t; j < NNODES; j += 256) bcounts[(size_t)j * NB + b] = lh[j];
}

// ---- scan: node offsets + per-block bases rewritten in place ----
__global__ void scan_kernel(int* __restrict__ bcounts, int* __restrict__ offsets) {
    int t = threadIdx.x;               // 0..1023, two nodes per thread
    int* p0 = bcounts + (size_t)(2 * t) * NB;
    int* p1 = p0 + NB;
    int sum0 = 0, sum1 = 0;
    for (int b = 0; b < NB; ++b) sum0 += p0[b];
    for (int b = 0; b < NB; ++b) sum1 += p1[b];
    int tot = sum0 + sum1;

    int lane = t & 63, wid = t >> 6;
    int x = tot;
#pragma unroll
    for (int d = 1; d < 64; d <<= 1) {
        int y = __shfl_up(x, d);
        if (lane >= d) x += y;
    }
    __shared__ int ws[16];
    if (lane == 63) ws[wid] = x;
    __syncthreads();
    int wbase = 0;
    for (int w = 0; w < wid; ++w) wbase += ws[w];
    int excl = wbase + x - tot;

    offsets[2 * t] = excl;
    offsets[2 * t + 1] = excl + sum0;
    if (t == 1023) offsets[NNODES] = excl + tot;

    int run = excl;
    for (int b = 0; b < NB; ++b) { int c = p0[b]; p0[b] = run; run += c; }
    run = excl + sum0;
    for (int b = 0; b < NB; ++b) { int c = p1[b]; p1[b] = run; run += c; }
}

// ---- pass B: scatter with LDS cursors (no global atomics) ----
__global__ void scatter_kernel(const int4* __restrict__ src4, const int4* __restrict__ dst4,
                               const int* __restrict__ bbase, int* __restrict__ src_sorted) {
    __shared__ int cur[NNODES];
    int b = blockIdx.x, t = threadIdx.x;
    for (int j = t; j < NNODES; j += 256) cur[j] = bbase[(size_t)j * NB + b];
    __syncthreads();
    const int4* ps = src4 + b * (EPB / 4);
    const int4* pd = dst4 + b * (EPB / 4);
    int4 s0 = ps[t], s1 = ps[t + 256];
    int4 d0 = pd[t], d1 = pd[t + 256];
    src_sorted[atomicAdd(&cur[d0.x], 1)] = s0.x;
    src_sorted[atomicAdd(&cur[d0.y], 1)] = s0.y;
    src_sorted[atomicAdd(&cur[d0.z], 1)] = s0.z;
    src_sorted[atomicAdd(&cur[d0.w], 1)] = s0.w;
    src_sorted[atomicAdd(&cur[d1.x], 1)] = s1.x;
    src_sorted[atomicAdd(&cur[d1.y], 1)] = s1.y;
    src_sorted[atomicAdd(&cur[d1.z], 1)] = s1.z;
    src_sorted[atomicAdd(&cur[d1.w], 1)] = s1.w;
}

// ---- main attention kernel ----
// Block = dst node, 4 waves; wave handles a contiguous chunk of the edge list.
// Lane: head = lane>>3, sub = lane&7 (8 dims). Per edge per wave: 2x dwordx4
// bf16 gather (k row 1KB + v row 1KB), 8-FMA dot, 3 shuffles, exp, 8 FMA acc.
// Software pipeline: src prefetched 2 ahead, k/v rows 1 ahead.
__global__ void __launch_bounds__(256, 6) attn_kernel(
    const float* __restrict__ q, const ushort* __restrict__ kc, const ushort* __restrict__ vc,
    const int* __restrict__ offsets, const int* __restrict__ src_sorted,
    float* __restrict__ out) {
    int node = blockIdx.x;
    int t = threadIdx.x;
    int w = t >> 6;
    int lane = t & 63;

    size_t qoff = (size_t)node * (NHEAD * DKDIM) + lane * 8;
    float4 q0 = *(const float4*)&q[qoff];
    float4 q1 = *(const float4*)&q[qoff + 4];

    int beg = offsets[node];
    int deg = offsets[node + 1] - beg;
    int cnt = (deg + 3) >> 2;
    int s = w * cnt;
    int eend = min(s + cnt, deg);
    int num = eend - s;

    const uint4* kb = (const uint4*)kc;   // row = 64 uint4; lane's slice = +lane
    const uint4* vb = (const uint4*)vc;

    float a0 = 0.f, a1 = 0.f, a2 = 0.f, a3 = 0.f;
    float a4 = 0.f, a5 = 0.f, a6 = 0.f, a7 = 0.f;
    float z = 0.f;

    auto compute = [&](uint4 kw, uint4 vw) {
        float p;
        p = BFLO(kw.x) * q0.x;
        p = fmaf(BFHI(kw.x), q0.y, p);
        p = fmaf(BFLO(kw.y), q0.z, p);
        p = fmaf(BFHI(kw.y), q0.w, p);
        p = fmaf(BFLO(kw.z), q1.x, p);
        p = fmaf(BFHI(kw.z), q1.y, p);
        p = fmaf(BFLO(kw.w), q1.z, p);
        p = fmaf(BFHI(kw.w), q1.w, p);
        p += __shfl_xor(p, 1);
        p += __shfl_xor(p, 2);
        p += __shfl_xor(p, 4);
        float sc = fminf(fmaxf(p, -10.f), 10.f);
        float sw = __expf(sc);
        a0 = fmaf(sw, BFLO(vw.x), a0);
        a1 = fmaf(sw, BFHI(vw.x), a1);
        a2 = fmaf(sw, BFLO(vw.y), a2);
        a3 = fmaf(sw, BFHI(vw.y), a3);
        a4 = fmaf(sw, BFLO(vw.z), a4);
        a5 = fmaf(sw, BFHI(vw.z), a5);
        a6 = fmaf(sw, BFLO(vw.w), a6);
        a7 = fmaf(sw, BFHI(vw.w), a7);
        z += sw;
    };

    if (num > 0) {
        int idx = beg + s;
        int src0 = src_sorted[idx];
        uint4 kcur = kb[(size_t)src0 * 64 + lane];
        uint4 vcur = vb[(size_t)src0 * 64 + lane];
        int srcn = (num > 1) ? src_sorted[idx + 1] : 0;
        for (int i = 0; i < num - 1; ++i) {
            uint4 knxt = kb[(size_t)srcn * 64 + lane];
            uint4 vnxt = vb[(size_t)srcn * 64 + lane];
            int srcn2 = (i + 2 < num) ? src_sorted[idx + i + 2] : 0;
            compute(kcur, vcur);
            kcur = knxt; vcur = vnxt; srcn = srcn2;
        }
        compute(kcur, vcur);
    }

    // cross-wave reduction
    __shared__ float racc[4][64][9];
    __shared__ float rz[4][8];
    float* row = &racc[w][lane][0];
    row[0] = a0; row[1] = a1; row[2] = a2; row[3] = a3;
    row[4] = a4; row[5] = a5; row[6] = a6; row[7] = a7;
    if ((lane & 7) == 0) rz[w][lane >> 3] = z;
    __syncthreads();

#pragma unroll
    for (int i = t; i < NHEAD * DKDIM; i += 256) {
        int l = i >> 3;
        int d8 = i & 7;
        int h = i >> 6;
        float sum = racc[0][l][d8] + racc[1][l][d8] + racc[2][l][d8] + racc[3][l][d8];
        float zz = rz[0][h] + rz[1][h] + rz[2][h] + rz[3][h];
        out[(size_t)node * NHEAD * DKDIM + i] = sum / zz;
    }
}

// ---------------- launch ----------------

extern "C" void kernel_launch(void* const* d_in, const int* in_sizes, int n_in,
                              void* d_out, int out_size, void* d_ws, size_t ws_size,
                              hipStream_t stream) {
    const float* q = (const float*)d_in[0];
    const float* k = (const float*)d_in[1];
    const float* v = (const float*)d_in[2];
    const int* esrc = (const int*)d_in[3];
    const int* edst = (const int*)d_in[4];
    float* out = (float*)d_out;

    // workspace layout (ints unless noted)
    int* offsets = (int*)d_ws;                       // 2052 (padded)
    int* bcounts = offsets + 2052;                   // NNODES*NB = 524288
    int* src_sorted = bcounts + NNODES * NB;         // E = 524288
    ushort* kc = (ushort*)(src_sorted + NB * EPB);   // 1M bf16
    ushort* vc = kc + NNODES * NHEAD * DKDIM;        // 1M bf16

    conv_kernel<<<2048, 256, 0, stream>>>((const float4*)k, (const float4*)v,
                                          (ushort4*)kc, (ushort4*)vc);
    hist_kernel<<<NB, 256, 0, stream>>>((const int4*)edst, bcounts);
    scan_kernel<<<1, 1024, 0, stream>>>(bcounts, offsets);
    scatter_kernel<<<NB, 256, 0, stream>>>((const int4*)esrc, (const int4*)edst,
                                           bcounts, src_sorted);
    attn_kernel<<<NNODES, 256, 0, stream>>>(q, kc, vc, offsets, src_sorted, out);
}

// Round 5
// 98.923 us; speedup vs baseline: 4.1856x; 2.9113x over previous
//
#include <hip/hip_runtime.h>

#define NNODES 2048
#define NHEAD 8
#define DKDIM 64
#define NB 256      // hist/scatter blocks
#define EPB 2048    // edges per block: NB*EPB = E = 524288

typedef unsigned int uint;
typedef unsigned short ushort;

__device__ __forceinline__ ushort f2bf(float f) {
    uint u = __float_as_uint(f);
    u = (u + 0x7FFFu + ((u >> 16) & 1u)) >> 16;   // RNE
    return (ushort)u;
}
#define BFLO(w) __uint_as_float((w) << 16)
#define BFHI(w) __uint_as_float((w) & 0xFFFF0000u)

// ---- k,v -> bf16 (k pre-scaled by 1/sqrt(64)) ----
__global__ void conv_kernel(const float4* __restrict__ kk, const float4* __restrict__ vv,
                            ushort4* __restrict__ kc, ushort4* __restrict__ vc) {
    int i = blockIdx.x * blockDim.x + threadIdx.x;   // 0 .. 524287
    if (i < 262144) {
        float4 x = kk[i];
        ushort4 o;
        o.x = f2bf(x.x * 0.125f); o.y = f2bf(x.y * 0.125f);
        o.z = f2bf(x.z * 0.125f); o.w = f2bf(x.w * 0.125f);
        kc[i] = o;
    } else {
        int j = i - 262144;
        float4 x = vv[j];
        ushort4 o;
        o.x = f2bf(x.x); o.y = f2bf(x.y); o.z = f2bf(x.z); o.w = f2bf(x.w);
        vc[j] = o;
    }
}

// ---- counting-sort CSR, pass A: LDS-private histogram, block-major output ----
__global__ void hist_kernel(const int4* __restrict__ dst4, int* __restrict__ bcounts) {
    __shared__ int lh[NNODES];
    int b = blockIdx.x, t = threadIdx.x;
    for (int j = t; j < NNODES; j += 256) lh[j] = 0;
    __syncthreads();
    const int4* p = dst4 + b * (EPB / 4);
    int4 d0 = p[t];
    int4 d1 = p[t + 256];
    atomicAdd(&lh[d0.x], 1); atomicAdd(&lh[d0.y], 1);
    atomicAdd(&lh[d0.z], 1); atomicAdd(&lh[d0.w], 1);
    atomicAdd(&lh[d1.x], 1); atomicAdd(&lh[d1.y], 1);
    atomicAdd(&lh[d1.z], 1); atomicAdd(&lh[d1.w], 1);
    __syncthreads();
    for (int j = t; j < NNODES; j += 256) bcounts[(size_t)b * NNODES + j] = lh[j];
}

// ---- scanA: per-node running base over blocks (in place), node totals out ----
// thread = node; coalesced across lanes; 256 serial iters with ILP via unroll
__global__ void scanA_kernel(int* __restrict__ bcounts, int* __restrict__ ntot) {
    int node = blockIdx.x * blockDim.x + threadIdx.x;   // 0..2047
    int run = 0;
#pragma unroll 8
    for (int b = 0; b < NB; ++b) {
        size_t off = (size_t)b * NNODES + node;
        int c = bcounts[off];
        bcounts[off] = run;
        run += c;
    }
    ntot[node] = run;
}

// ---- scanB: exclusive scan of 2048 node totals -> offsets ----
__global__ void scanB_kernel(const int* __restrict__ ntot, int* __restrict__ offsets) {
    int t = threadIdx.x;                 // 0..1023, two nodes per thread
    int s0 = ntot[2 * t], s1 = ntot[2 * t + 1];
    int tot = s0 + s1;
    int lane = t & 63, wid = t >> 6;
    int x = tot;
#pragma unroll
    for (int d = 1; d < 64; d <<= 1) {
        int y = __shfl_up(x, d);
        if (lane >= d) x += y;
    }
    __shared__ int ws[16];
    if (lane == 63) ws[wid] = x;
    __syncthreads();
    int wbase = 0;
    for (int w = 0; w < wid; ++w) wbase += ws[w];
    int excl = wbase + x - tot;
    offsets[2 * t] = excl;
    offsets[2 * t + 1] = excl + s0;
    if (t == 1023) offsets[NNODES] = excl + tot;
}

// ---- pass B: scatter with LDS cursors (no global atomics) ----
__global__ void scatter_kernel(const int4* __restrict__ src4, const int4* __restrict__ dst4,
                               const int* __restrict__ bbase, const int* __restrict__ offsets,
                               int* __restrict__ src_sorted) {
    __shared__ int cur[NNODES];
    int b = blockIdx.x, t = threadIdx.x;
    for (int j = t; j < NNODES; j += 256)
        cur[j] = bbase[(size_t)b * NNODES + j] + offsets[j];
    __syncthreads();
    const int4* ps = src4 + b * (EPB / 4);
    const int4* pd = dst4 + b * (EPB / 4);
    int4 s0 = ps[t], s1 = ps[t + 256];
    int4 d0 = pd[t], d1 = pd[t + 256];
    src_sorted[atomicAdd(&cur[d0.x], 1)] = s0.x;
    src_sorted[atomicAdd(&cur[d0.y], 1)] = s0.y;
    src_sorted[atomicAdd(&cur[d0.z], 1)] = s0.z;
    src_sorted[atomicAdd(&cur[d0.w], 1)] = s0.w;
    src_sorted[atomicAdd(&cur[d1.x], 1)] = s1.x;
    src_sorted[atomicAdd(&cur[d1.y], 1)] = s1.y;
    src_sorted[atomicAdd(&cur[d1.z], 1)] = s1.z;
    src_sorted[atomicAdd(&cur[d1.w], 1)] = s1.w;
}

// ---- main attention kernel ----
// Block = dst node, 4 waves; wave handles a contiguous chunk of the edge list.
// Lane: head = lane>>3, sub = lane&7 (8 dims). Per edge per wave: 2x dwordx4
// bf16 gather (k row 1KB + v row 1KB), 8-FMA dot, 3 shuffles, exp, 8 FMA acc.
// Software pipeline: src prefetched 2 ahead, k/v rows 1 ahead.
__global__ void __launch_bounds__(256, 6) attn_kernel(
    const float* __restrict__ q, const ushort* __restrict__ kc, const ushort* __restrict__ vc,
    const int* __restrict__ offsets, const int* __restrict__ src_sorted,
    float* __restrict__ out) {
    int node = blockIdx.x;
    int t = threadIdx.x;
    int w = t >> 6;
    int lane = t & 63;

    size_t qoff = (size_t)node * (NHEAD * DKDIM) + lane * 8;
    float4 q0 = *(const float4*)&q[qoff];
    float4 q1 = *(const float4*)&q[qoff + 4];

    int beg = offsets[node];
    int deg = offsets[node + 1] - beg;
    int cnt = (deg + 3) >> 2;
    int s = w * cnt;
    int eend = min(s + cnt, deg);
    int num = eend - s;

    const uint4* kb = (const uint4*)kc;   // row = 64 uint4; lane's slice = +lane
    const uint4* vb = (const uint4*)vc;

    float a0 = 0.f, a1 = 0.f, a2 = 0.f, a3 = 0.f;
    float a4 = 0.f, a5 = 0.f, a6 = 0.f, a7 = 0.f;
    float z = 0.f;

    auto compute = [&](uint4 kw, uint4 vw) {
        float p;
        p = BFLO(kw.x) * q0.x;
        p = fmaf(BFHI(kw.x), q0.y, p);
        p = fmaf(BFLO(kw.y), q0.z, p);
        p = fmaf(BFHI(kw.y), q0.w, p);
        p = fmaf(BFLO(kw.z), q1.x, p);
        p = fmaf(BFHI(kw.z), q1.y, p);
        p = fmaf(BFLO(kw.w), q1.z, p);
        p = fmaf(BFHI(kw.w), q1.w, p);
        p += __shfl_xor(p, 1);
        p += __shfl_xor(p, 2);
        p += __shfl_xor(p, 4);
        float sc = fminf(fmaxf(p, -10.f), 10.f);
        float sw = __expf(sc);
        a0 = fmaf(sw, BFLO(vw.x), a0);
        a1 = fmaf(sw, BFHI(vw.x), a1);
        a2 = fmaf(sw, BFLO(vw.y), a2);
        a3 = fmaf(sw, BFHI(vw.y), a3);
        a4 = fmaf(sw, BFLO(vw.z), a4);
        a5 = fmaf(sw, BFHI(vw.z), a5);
        a6 = fmaf(sw, BFLO(vw.w), a6);
        a7 = fmaf(sw, BFHI(vw.w), a7);
        z += sw;
    };

    if (num > 0) {
        int idx = beg + s;
        int src0 = src_sorted[idx];
        uint4 kcur = kb[(size_t)src0 * 64 + lane];
        uint4 vcur = vb[(size_t)src0 * 64 + lane];
        int srcn = (num > 1) ? src_sorted[idx + 1] : 0;
        for (int i = 0; i < num - 1; ++i) {
            uint4 knxt = kb[(size_t)srcn * 64 + lane];
            uint4 vnxt = vb[(size_t)srcn * 64 + lane];
            int srcn2 = (i + 2 < num) ? src_sorted[idx + i + 2] : 0;
            compute(kcur, vcur);
            kcur = knxt; vcur = vnxt; srcn = srcn2;
        }
        compute(kcur, vcur);
    }

    // cross-wave reduction
    __shared__ float racc[4][64][9];
    __shared__ float rz[4][8];
    float* row = &racc[w][lane][0];
    row[0] = a0; row[1] = a1; row[2] = a2; row[3] = a3;
    row[4] = a4; row[5] = a5; row[6] = a6; row[7] = a7;
    if ((lane & 7) == 0) rz[w][lane >> 3] = z;
    __syncthreads();

#pragma unroll
    for (int i = t; i < NHEAD * DKDIM; i += 256) {
        int l = i >> 3;
        int d8 = i & 7;
        int h = i >> 6;
        float sum = racc[0][l][d8] + racc[1][l][d8] + racc[2][l][d8] + racc[3][l][d8];
        float zz = rz[0][h] + rz[1][h] + rz[2][h] + rz[3][h];
        out[(size_t)node * NHEAD * DKDIM + i] = sum / zz;
    }
}

// ---------------- launch ----------------

extern "C" void kernel_launch(void* const* d_in, const int* in_sizes, int n_in,
                              void* d_out, int out_size, void* d_ws, size_t ws_size,
                              hipStream_t stream) {
    const float* q = (const float*)d_in[0];
    const float* k = (const float*)d_in[1];
    const float* v = (const float*)d_in[2];
    const int* esrc = (const int*)d_in[3];
    const int* edst = (const int*)d_in[4];
    float* out = (float*)d_out;

    // workspace layout
    int* offsets = (int*)d_ws;                        // 2052 (padded)
    int* ntot = offsets + 2052;                       // 2048
    int* bcounts = ntot + NNODES;                     // NB*NNODES = 524288
    int* src_sorted = bcounts + NB * NNODES;          // E = 524288
    ushort* kc = (ushort*)(src_sorted + NB * EPB);    // 1M bf16
    ushort* vc = kc + NNODES * NHEAD * DKDIM;         // 1M bf16

    conv_kernel<<<2048, 256, 0, stream>>>((const float4*)k, (const float4*)v,
                                          (ushort4*)kc, (ushort4*)vc);
    hist_kernel<<<NB, 256, 0, stream>>>((const int4*)edst, bcounts);
    scanA_kernel<<<NNODES / 256, 256, 0, stream>>>(bcounts, ntot);
    scanB_kernel<<<1, 1024, 0, stream>>>(ntot, offsets);
    scatter_kernel<<<NB, 256, 0, stream>>>((const int4*)esrc, (const int4*)edst,
                                           bcounts, offsets, src_sorted);
    attn_kernel<<<NNODES, 256, 0, stream>>>(q, kc, vc, offsets, src_sorted, out);
}

// Round 7
// 96.804 us; speedup vs baseline: 4.2772x; 1.0219x over previous
//
#include <hip/hip_runtime.h>

#define NNODES 2048
#define NHEAD 8
#define DKDIM 64
#define NB 256      // hist/scatter blocks
#define EPB 2048    // edges per block: NB*EPB = E = 524288

typedef unsigned int uint;
typedef unsigned short ushort;
typedef __fp16 h2 __attribute__((ext_vector_type(2)));

#define KSCALE 0.18033688011112042f   // 0.125 * log2(e)
#define CLAMP2 14.426950408889634f    // 10 * log2(e)

__device__ __forceinline__ h2 bch2(uint u) {
    union { uint u; h2 h; } x; x.u = u; return x.h;
}
__device__ __forceinline__ uint pk2(float a, float b) {
#if __has_builtin(__builtin_amdgcn_cvt_pkrtz)
    union { h2 h; uint u; } x; x.h = __builtin_amdgcn_cvt_pkrtz(a, b); return x.u;
#else
    union { __fp16 h[2]; uint u; } x; x.h[0] = (__fp16)a; x.h[1] = (__fp16)b; return x.u;
#endif
}
__device__ __forceinline__ float dot2(uint k, uint q, float c) {
#if __has_builtin(__builtin_amdgcn_fdot2)
    return __builtin_amdgcn_fdot2(bch2(k), bch2(q), c, false);
#else
    h2 kk = bch2(k), qq = bch2(q);
    return fmaf((float)kk[0], (float)qq[0], fmaf((float)kk[1], (float)qq[1], c));
#endif
}

// ---- k,v -> fp16 (k pre-scaled by 0.125*log2e) ----
__global__ void conv_kernel(const float4* __restrict__ kk, const float4* __restrict__ vv,
                            uint2* __restrict__ kc, uint2* __restrict__ vc) {
    int i = blockIdx.x * blockDim.x + threadIdx.x;   // 0 .. 524287
    if (i < 262144) {
        float4 x = kk[i];
        uint2 o = { pk2(x.x * KSCALE, x.y * KSCALE), pk2(x.z * KSCALE, x.w * KSCALE) };
        kc[i] = o;
    } else {
        int j = i - 262144;
        float4 x = vv[j];
        uint2 o = { pk2(x.x, x.y), pk2(x.z, x.w) };
        vc[j] = o;
    }
}

// ---- counting-sort CSR, pass A: LDS-private histogram, block-major output ----
__global__ void hist_kernel(const int4* __restrict__ dst4, int* __restrict__ bcounts) {
    __shared__ int lh[NNODES];
    int b = blockIdx.x, t = threadIdx.x;
    for (int j = t; j < NNODES; j += 256) lh[j] = 0;
    __syncthreads();
    const int4* p = dst4 + b * (EPB / 4);
    int4 d0 = p[t];
    int4 d1 = p[t + 256];
    atomicAdd(&lh[d0.x], 1); atomicAdd(&lh[d0.y], 1);
    atomicAdd(&lh[d0.z], 1); atomicAdd(&lh[d0.w], 1);
    atomicAdd(&lh[d1.x], 1); atomicAdd(&lh[d1.y], 1);
    atomicAdd(&lh[d1.z], 1); atomicAdd(&lh[d1.w], 1);
    __syncthreads();
    for (int j = t; j < NNODES; j += 256) bcounts[(size_t)b * NNODES + j] = lh[j];
}

// ---- scanA: per-node running base over blocks (in place), node totals out ----
__global__ void scanA_kernel(int* __restrict__ bcounts, int* __restrict__ ntot) {
    int node = blockIdx.x * blockDim.x + threadIdx.x;   // 0..2047
    int run = 0;
#pragma unroll 8
    for (int b = 0; b < NB; ++b) {
        size_t off = (size_t)b * NNODES + node;
        int c = bcounts[off];
        bcounts[off] = run;
        run += c;
    }
    ntot[node] = run;
}

// ---- scanB: exclusive scan of 2048 node totals -> offsets ----
__global__ void scanB_kernel(const int* __restrict__ ntot, int* __restrict__ offsets) {
    int t = threadIdx.x;                 // 0..1023, two nodes per thread
    int s0 = ntot[2 * t], s1 = ntot[2 * t + 1];
    int tot = s0 + s1;
    int lane = t & 63, wid = t >> 6;
    int x = tot;
#pragma unroll
    for (int d = 1; d < 64; d <<= 1) {
        int y = __shfl_up(x, d);
        if (lane >= d) x += y;
    }
    __shared__ int ws[16];
    if (lane == 63) ws[wid] = x;
    __syncthreads();
    int wbase = 0;
    for (int w = 0; w < wid; ++w) wbase += ws[w];
    int excl = wbase + x - tot;
    offsets[2 * t] = excl;
    offsets[2 * t + 1] = excl + s0;
    if (t == 1023) offsets[NNODES] = excl + tot;
}

// ---- pass B: scatter with LDS cursors (no global atomics) ----
__global__ void scatter_kernel(const int4* __restrict__ src4, const int4* __restrict__ dst4,
                               const int* __restrict__ bbase, const int* __restrict__ offsets,
                               int* __restrict__ src_sorted) {
    __shared__ int cur[NNODES];
    int b = blockIdx.x, t = threadIdx.x;
    for (int j = t; j < NNODES; j += 256)
        cur[j] = bbase[(size_t)b * NNODES + j] + offsets[j];
    __syncthreads();
    const int4* ps = src4 + b * (EPB / 4);
    const int4* pd = dst4 + b * (EPB / 4);
    int4 s0 = ps[t], s1 = ps[t + 256];
    int4 d0 = pd[t], d1 = pd[t + 256];
    src_sorted[atomicAdd(&cur[d0.x], 1)] = s0.x;
    src_sorted[atomicAdd(&cur[d0.y], 1)] = s0.y;
    src_sorted[atomicAdd(&cur[d0.z], 1)] = s0.z;
    src_sorted[atomicAdd(&cur[d0.w], 1)] = s0.w;
    src_sorted[atomicAdd(&cur[d1.x], 1)] = s1.x;
    src_sorted[atomicAdd(&cur[d1.y], 1)] = s1.y;
    src_sorted[atomicAdd(&cur[d1.z], 1)] = s1.z;
    src_sorted[atomicAdd(&cur[d1.w], 1)] = s1.w;
}

// ---- main attention kernel ----
// Block = dst node, 4 waves; wave handles a contiguous chunk of the edge list.
// Lane: head = lane>>3, sub = lane&7 (8 dims, fp16). Per edge per wave:
// 2x dwordx4 gather (k,v rows), 4x v_dot2_f32_f16, 3 shuffles, exp2,
// 8x v_fma_mix acc. Software pipeline: src +2 ahead, k/v rows +1 ahead.
__global__ void __launch_bounds__(256, 8) attn_kernel(
    const float* __restrict__ q, const uint4* __restrict__ kb, const uint4* __restrict__ vb,
    const int* __restrict__ offsets, const int* __restrict__ src_sorted,
    float* __restrict__ out) {
    int node = blockIdx.x;
    int t = threadIdx.x;
    int w = t >> 6;
    int lane = t & 63;

    size_t qoff = (size_t)node * (NHEAD * DKDIM) + lane * 8;
    float4 qa = *(const float4*)&q[qoff];
    float4 qb = *(const float4*)&q[qoff + 4];
    uint4 qw;
    qw.x = pk2(qa.x, qa.y);
    qw.y = pk2(qa.z, qa.w);
    qw.z = pk2(qb.x, qb.y);
    qw.w = pk2(qb.z, qb.w);

    int beg = offsets[node];
    int deg = offsets[node + 1] - beg;
    int cnt = (deg + 3) >> 2;
    int s = w * cnt;
    int eend = min(s + cnt, deg);
    int num = eend - s;

    float a0 = 0.f, a1 = 0.f, a2 = 0.f, a3 = 0.f;
    float a4 = 0.f, a5 = 0.f, a6 = 0.f, a7 = 0.f;
    float z = 0.f;

    auto compute = [&](uint4 kw, uint4 vw) {
        float p = dot2(kw.x, qw.x, 0.f);
        p = dot2(kw.y, qw.y, p);
        p = dot2(kw.z, qw.z, p);
        p = dot2(kw.w, qw.w, p);
        p += __shfl_xor(p, 1);
        p += __shfl_xor(p, 2);
        p += __shfl_xor(p, 4);
        float sc = fminf(fmaxf(p, -CLAMP2), CLAMP2);
        float sw = exp2f(sc);
        h2 v0 = bch2(vw.x), v1 = bch2(vw.y), v2 = bch2(vw.z), v3 = bch2(vw.w);
        a0 = fmaf(sw, (float)v0[0], a0);
        a1 = fmaf(sw, (float)v0[1], a1);
        a2 = fmaf(sw, (float)v1[0], a2);
        a3 = fmaf(sw, (float)v1[1], a3);
        a4 = fmaf(sw, (float)v2[0], a4);
        a5 = fmaf(sw, (float)v2[1], a5);
        a6 = fmaf(sw, (float)v3[0], a6);
        a7 = fmaf(sw, (float)v3[1], a7);
        z += sw;
    };

    if (num > 0) {
        int idx = beg + s;
        int src0 = src_sorted[idx];
        uint4 kcur = kb[(size_t)src0 * 64 + lane];
        uint4 vcur = vb[(size_t)src0 * 64 + lane];
        int srcn = (num > 1) ? src_sorted[idx + 1] : 0;
        for (int i = 0; i < num - 1; ++i) {
            uint4 knxt = kb[(size_t)srcn * 64 + lane];
            uint4 vnxt = vb[(size_t)srcn * 64 + lane];
            int srcn2 = (i + 2 < num) ? src_sorted[idx + i + 2] : 0;
            compute(kcur, vcur);
            kcur = knxt; vcur = vnxt; srcn = srcn2;
        }
        compute(kcur, vcur);
    }

    // cross-wave reduction
    __shared__ float racc[4][64][9];
    __shared__ float rz[4][8];
    float* row = &racc[w][lane][0];
    row[0] = a0; row[1] = a1; row[2] = a2; row[3] = a3;
    row[4] = a4; row[5] = a5; row[6] = a6; row[7] = a7;
    if ((lane & 7) == 0) rz[w][lane >> 3] = z;
    __syncthreads();

#pragma unroll
    for (int i = t; i < NHEAD * DKDIM; i += 256) {
        int l = i >> 3;
        int d8 = i & 7;
        int h = i >> 6;
        float sum = racc[0][l][d8] + racc[1][l][d8] + racc[2][l][d8] + racc[3][l][d8];
        float zz = rz[0][h] + rz[1][h] + rz[2][h] + rz[3][h];
        out[(size_t)node * NHEAD * DKDIM + i] = sum / zz;
    }
}

// ---------------- launch ----------------

extern "C" void kernel_launch(void* const* d_in, const int* in_sizes, int n_in,
                              void* d_out, int out_size, void* d_ws, size_t ws_size,
                              hipStream_t stream) {
    const float* q = (const float*)d_in[0];
    const float* k = (const float*)d_in[1];
    const float* v = (const float*)d_in[2];
    const int* esrc = (const int*)d_in[3];
    const int* edst = (const int*)d_in[4];
    float* out = (float*)d_out;

    // workspace layout
    int* offsets = (int*)d_ws;                        // 2052 (padded)
    int* ntot = offsets + 2052;                       // 2048
    int* bcounts = ntot + NNODES;                     // NB*NNODES = 524288
    int* src_sorted = bcounts + NB * NNODES;          // E = 524288
    ushort* kc = (ushort*)(src_sorted + NB * EPB);    // 1M fp16
    ushort* vc = kc + NNODES * NHEAD * DKDIM;         // 1M fp16

    conv_kernel<<<2048, 256, 0, stream>>>((const float4*)k, (const float4*)v,
                                          (uint2*)kc, (uint2*)vc);
    hist_kernel<<<NB, 256, 0, stream>>>((const int4*)edst, bcounts);
    scanA_kernel<<<NNODES / 256, 256, 0, stream>>>(bcounts, ntot);
    scanB_kernel<<<1, 1024, 0, stream>>>(ntot, offsets);
    scatter_kernel<<<NB, 256, 0, stream>>>((const int4*)esrc, (const int4*)edst,
                                           bcounts, offsets, src_sorted);
    attn_kernel<<<NNODES, 256, 0, stream>>>(q, (const uint4*)kc, (const uint4*)vc,
                                            offsets, src_sorted, out);
}